// Round 5
// baseline (34.742 us; speedup 1.0000x reference)
//
#include <hip/hip_runtime.h>
#include <hip/hip_bf16.h>
#include <math.h>

namespace {

typedef __bf16 bf16x8 __attribute__((ext_vector_type(8)));
typedef float f32x4 __attribute__((ext_vector_type(4)));

constexpr int L = 64;
constexpr int DH = 64;

// Swizzle key: distinct across BOTH stride-1 and stride-4 row sequences.
__device__ __forceinline__ int kkey(int r) { return (r ^ (r >> 2)) & 7; }
// Per-wave C tile: 16 rows x 64 cols, bf16, 128B rows, XOR-swizzled.
__device__ __forceinline__ int swzC(int r, int j) {
  return r * 128 + ((((j >> 3) ^ kkey(r)) & 7) << 4) + (j & 7) * 2;
}

__device__ __forceinline__ unsigned short bfbits(float f) {
  __bf16 h = (__bf16)f;
  return __builtin_bit_cast(unsigned short, h);
}
__device__ __forceinline__ __bf16 tobf(float f) { return (__bf16)f; }

__global__ __launch_bounds__(256, 4) void mlstm_mfma(
    const float* __restrict__ q, const float* __restrict__ k,
    const float* __restrict__ v, const float* __restrict__ ig,
    const float* __restrict__ fg, float* __restrict__ out) {

  // 4 waves per chunk; wave w owns output rows [16w, 16w+16).
  // NO barriers, NO cross-wave data. LDS = per-wave 2KB C tile only.
  __shared__ __align__(16) char lds[4 * 2048];

  const int tid = threadIdx.x;
  const int w = tid >> 6;    // wave id = output row-block (cb)
  const int lane = tid & 63;
  const int m = lane & 15;
  const int g = lane >> 4;
  const size_t cbase = (size_t)blockIdx.x * (L * DH);
  const size_t gb = (size_t)blockIdx.x * L;

  // ---- gate loads first (head of the longest dependent chain) -----------
  const float fgv = fg[gb + lane];
  const float igv = ig[gb + lane];

  // ---- V^T fragments via strided global loads (no LDS, no barrier) ------
  // mm2 A-frag: lane (m,g) needs V^T[d=db*16+m][j=jb*32+g*8+t] = V[j][d].
  const int njb = (w >= 2) ? 2 : 1;
  float vtmp[4][2][8];
#pragma unroll
  for (int db = 0; db < 4; ++db)
#pragma unroll
    for (int jb = 0; jb < 2; ++jb)
      if (jb < njb) {
        const float* vp =
            v + cbase + (size_t)(jb * 32 + g * 8) * 64 + db * 16 + m;
#pragma unroll
        for (int t = 0; t < 8; ++t) vtmp[db][jb][t] = vp[t * 64];
      }

  // ---- Q (own rows) and K (rb <= w) fragments, float4 + cvt bf16 --------
  bf16x8 qf[2];
#pragma unroll
  for (int kb = 0; kb < 2; ++kb) {
    const int off = (w * 16 + m) * 64 + kb * 32 + g * 8;
    const float4 q0 = *(const float4*)(q + cbase + off);
    const float4 q1 = *(const float4*)(q + cbase + off + 4);
    qf[kb] = bf16x8{tobf(q0.x), tobf(q0.y), tobf(q0.z), tobf(q0.w),
                    tobf(q1.x), tobf(q1.y), tobf(q1.z), tobf(q1.w)};
  }
  bf16x8 kf[4][2];
#pragma unroll
  for (int rb = 0; rb < 4; ++rb) {
    if (rb <= w) {  // wave-uniform
#pragma unroll
      for (int kb = 0; kb < 2; ++kb) {
        const int off = (rb * 16 + m) * 64 + kb * 32 + g * 8;
        const float4 k0 = *(const float4*)(k + cbase + off);
        const float4 k1 = *(const float4*)(k + cbase + off + 4);
        kf[rb][kb] = bf16x8{tobf(k0.x), tobf(k0.y), tobf(k0.z), tobf(k0.w),
                            tobf(k1.x), tobf(k1.y), tobf(k1.z), tobf(k1.w)};
      }
    }
  }

  // ---- per-wave gate scan (redundant across waves; removes coupling) ----
  float ea, eb, em;  // lane l holds values for time index l
  {
    const float lf = fminf(fgv, 0.f) - log1pf(__expf(-fabsf(fgv)));
    float cum = lf;  // inclusive prefix sum of log f
#pragma unroll
    for (int o = 1; o < 64; o <<= 1) {
      const float t = __shfl_up(cum, o, 64);
      if (lane >= o) cum += t;
    }
    const float a = igv - cum;
    float b = a;  // inclusive prefix max
#pragma unroll
    for (int o = 1; o < 64; o <<= 1) {
      const float t = __shfl_up(b, o, 64);
      if (lane >= o) b = fmaxf(b, t);
    }
    const float bmax = __shfl(b, 63, 64);
    ea = 0.125f * __expf(a - bmax);  // fold 1/sqrt(DH)
    eb = __expf(bmax - b);
    em = __expf(-(b + cum));
  }

  // ---- cvt V fragments to bf16 -------------------------------------------
  bf16x8 vfr[4][2];
#pragma unroll
  for (int db = 0; db < 4; ++db)
#pragma unroll
    for (int jb = 0; jb < 2; ++jb)
      if (jb < njb) {
        const float* t = vtmp[db][jb];
        vfr[db][jb] = bf16x8{tobf(t[0]), tobf(t[1]), tobf(t[2]), tobf(t[3]),
                             tobf(t[4]), tobf(t[5]), tobf(t[6]), tobf(t[7])};
      }

  // ---- mm1: S^T tiles for cb = w, rb <= w ---------------------------------
  f32x4 st[4];
#pragma unroll
  for (int rb = 0; rb < 4; ++rb) {
    if (rb <= w) {
      f32x4 acc = {0.f, 0.f, 0.f, 0.f};
      acc = __builtin_amdgcn_mfma_f32_16x16x32_bf16(kf[rb][0], qf[0], acc, 0, 0, 0);
      acc = __builtin_amdgcn_mfma_f32_16x16x32_bf16(kf[rb][1], qf[1], acc, 0, 0, 0);
      st[rb] = acc;
    }
  }

  // ---- gating, C write (own 16 rows), stabilized normalizer --------------
  char* cw = lds + w * 2048;
  const int i = w * 16 + m;
  const float ebv = __shfl(eb, i, 64);
  const float emv = __shfl(em, i, 64);
  float rs = 0.f;
  const int rbfill = w | 1;  // zero-fill the jb ranges mm2 will read
#pragma unroll
  for (int rb = 0; rb < 4; ++rb) {
    if (rb <= rbfill) {
      unsigned long long wp = 0ull;
      if (rb <= w) {
#pragma unroll
        for (int e = 0; e < 4; ++e) {
          const int j = rb * 16 + g * 4 + e;
          const float eaj = __shfl(ea, j, 64);
          const float val = (j <= i) ? st[rb][e] * eaj * ebv : 0.f;
          rs += val;
          wp |= (unsigned long long)bfbits(val) << (16 * e);
        }
      }
      *(unsigned long long*)(cw + swzC(m, rb * 16 + g * 4)) = wp;
    }
  }
  rs += __shfl_xor(rs, 16, 64);
  rs += __shfl_xor(rs, 32, 64);
  const float invv = 1.f / (fmaxf(fabsf(rs), emv) + 1e-6f);

  // ---- mm2: H^T block for i in [16w,16w+16) -------------------------------
  const bf16x8 c0 = *(const bf16x8*)(cw + swzC(m, g * 8));
  f32x4 acc[4];
#pragma unroll
  for (int db = 0; db < 4; ++db) {
    f32x4 z = {0.f, 0.f, 0.f, 0.f};
    acc[db] = __builtin_amdgcn_mfma_f32_16x16x32_bf16(vfr[db][0], c0, z, 0, 0, 0);
  }
  if (w >= 2) {
    const bf16x8 c1 = *(const bf16x8*)(cw + swzC(m, 32 + g * 8));
#pragma unroll
    for (int db = 0; db < 4; ++db)
      acc[db] = __builtin_amdgcn_mfma_f32_16x16x32_bf16(vfr[db][1], c1, acc[db], 0, 0, 0);
  }

  // ---- normalize + store (float4, coalesced) ------------------------------
  float* op = out + cbase + i * 64 + g * 4;
#pragma unroll
  for (int db = 0; db < 4; ++db) {
    const f32x4 hv = acc[db];
    *(float4*)(op + db * 16) =
        make_float4(hv[0] * invv, hv[1] * invv, hv[2] * invv, hv[3] * invv);
  }
}

}  // namespace

extern "C" void kernel_launch(void* const* d_in, const int* in_sizes, int n_in,
                              void* d_out, int out_size, void* d_ws,
                              size_t ws_size, hipStream_t stream) {
  const float* q = (const float*)d_in[0];
  const float* k = (const float*)d_in[1];
  const float* v = (const float*)d_in[2];
  const float* ig = (const float*)d_in[3];
  const float* fg = (const float*)d_in[4];
  float* out = (float*)d_out;

  const int total = in_sizes[0];         // B*NH*S*DH
  const int nchunks = total / (L * DH);  // 2048
  mlstm_mfma<<<dim3(nchunks), dim3(256), 0, stream>>>(q, k, v, ig, fg, out);
}

// Round 6
// 27.683 us; speedup vs baseline: 1.2550x; 1.2550x over previous
//
#include <hip/hip_runtime.h>
#include <hip/hip_bf16.h>
#include <math.h>

namespace {

typedef __bf16 bf16x8 __attribute__((ext_vector_type(8)));
typedef float f32x4 __attribute__((ext_vector_type(4)));

constexpr int L = 64;
constexpr int DH = 64;

// Swizzle key: distinct across BOTH stride-1 and stride-4 row sequences.
__device__ __forceinline__ int kkey(int r) { return (r ^ (r >> 2)) & 7; }
// V^T tile: 64 rows (d) x 64 cols (j), bf16, 128B rows, XOR-swizzled.
__device__ __forceinline__ int swzV(int d, int j) {
  return d * 128 + ((((j >> 3) ^ kkey(d)) & 7) << 4) + (j & 7) * 2;
}
// C tile: 64 rows (i) x 64 cols (j), bf16, 128B rows, XOR-swizzled.
__device__ __forceinline__ int swzC(int r, int j) {
  return r * 128 + ((((j >> 3) ^ kkey(r)) & 7) << 4) + (j & 7) * 2;
}

__device__ __forceinline__ unsigned short bfbits(float f) {
  __bf16 h = (__bf16)f;
  return __builtin_bit_cast(unsigned short, h);
}
__device__ __forceinline__ __bf16 tobf(float f) { return (__bf16)f; }

// One wave = one 64x64 chunk; grid caps residency at 8 waves/CU = 2/SIMD,
// so allow 256 VGPRs (launch_bounds min-waves/EU = 2) and hold ALL global
// loads in registers at once: a single pipelined memory event per wave
// instead of 3-4 serial HBM round-trips at the old 128-VGPR budget.
__global__ __launch_bounds__(64, 2) void mlstm_mfma(
    const float* __restrict__ q, const float* __restrict__ k,
    const float* __restrict__ v, const float* __restrict__ ig,
    const float* __restrict__ fg, float* __restrict__ out) {

  __shared__ __align__(16) char vt_raw[64 * 128];  // V^T bf16, swizzled
  __shared__ __align__(16) char cs_raw[64 * 128];  // C   bf16, swizzled
  __shared__ __align__(16) float ea_sh[64];
  __shared__ float eb_sh[64], em_sh[64];

  const int lane = threadIdx.x;
  const int m = lane & 15;   // fragment row/col index
  const int g = lane >> 4;   // fragment k-group
  const size_t cbase = (size_t)blockIdx.x * (L * DH);
  const size_t gb = (size_t)blockIdx.x * L;

  // ======== phase 0: issue EVERY global load up front (max MLP) ==========
  const float fgv = fg[gb + lane];
  const float igv = ig[gb + lane];

  const float4* v4 = (const float4*)(v + cbase);
  float4 vbuf[16];
#pragma unroll
  for (int it = 0; it < 16; ++it) vbuf[it] = v4[it * 64 + lane];

  float4 qbuf[4][2][2], kbuf[4][2][2];
#pragma unroll
  for (int rb = 0; rb < 4; ++rb)
#pragma unroll
    for (int kb = 0; kb < 2; ++kb) {
      const int off = (rb * 16 + m) * 64 + kb * 32 + g * 8;
      qbuf[rb][kb][0] = *(const float4*)(q + cbase + off);
      qbuf[rb][kb][1] = *(const float4*)(q + cbase + off + 4);
      kbuf[rb][kb][0] = *(const float4*)(k + cbase + off);
      kbuf[rb][kb][1] = *(const float4*)(k + cbase + off + 4);
    }

  // ======== gate scan (only needs fgv/igv — the first loads) =============
  {
    const float lf = fminf(fgv, 0.f) - log1pf(__expf(-fabsf(fgv)));
    float cum = lf;  // inclusive prefix sum of log f
#pragma unroll
    for (int o = 1; o < 64; o <<= 1) {
      const float t = __shfl_up(cum, o, 64);
      if (lane >= o) cum += t;
    }
    const float a = igv - cum;
    float b = a;  // inclusive prefix max
#pragma unroll
    for (int o = 1; o < 64; o <<= 1) {
      const float t = __shfl_up(b, o, 64);
      if (lane >= o) b = fmaxf(b, t);
    }
    const float bmax = __shfl(b, 63, 64);
    ea_sh[lane] = 0.125f * __expf(a - bmax);  // fold 1/sqrt(DH)
    eb_sh[lane] = __expf(bmax - b);
    em_sh[lane] = __expf(-(b + cum));
  }

  // ======== V^T scatter into LDS (bf16, swizzled) =========================
  {
    unsigned short* vt = (unsigned short*)vt_raw;
#pragma unroll
    for (int it = 0; it < 16; ++it) {
      const int idx = it * 64 + lane;  // float4 index in the chunk
      const int j = idx >> 4;          // time index
      const int d0 = (idx & 15) * 4;   // feature
      vt[swzV(d0 + 0, j) >> 1] = bfbits(vbuf[it].x);
      vt[swzV(d0 + 1, j) >> 1] = bfbits(vbuf[it].y);
      vt[swzV(d0 + 2, j) >> 1] = bfbits(vbuf[it].z);
      vt[swzV(d0 + 3, j) >> 1] = bfbits(vbuf[it].w);
    }
  }

  // ======== cvt Q/K to bf16 fragments =====================================
  bf16x8 qf[4][2], kf[4][2];
#pragma unroll
  for (int rb = 0; rb < 4; ++rb)
#pragma unroll
    for (int kb = 0; kb < 2; ++kb) {
      const float4 q0 = qbuf[rb][kb][0], q1 = qbuf[rb][kb][1];
      const float4 k0 = kbuf[rb][kb][0], k1 = kbuf[rb][kb][1];
      qf[rb][kb] = bf16x8{tobf(q0.x), tobf(q0.y), tobf(q0.z), tobf(q0.w),
                          tobf(q1.x), tobf(q1.y), tobf(q1.z), tobf(q1.w)};
      kf[rb][kb] = bf16x8{tobf(k0.x), tobf(k0.y), tobf(k0.z), tobf(k0.w),
                          tobf(k1.x), tobf(k1.y), tobf(k1.z), tobf(k1.w)};
    }

  // ======== mm1: S^T tiles (only rb <= cb are causal) =====================
  f32x4 st[4][4];
#pragma unroll
  for (int cb = 0; cb < 4; ++cb)
#pragma unroll
    for (int rb = 0; rb < 4; ++rb) {
      if (rb > cb) continue;
      f32x4 acc = {0.f, 0.f, 0.f, 0.f};
      acc = __builtin_amdgcn_mfma_f32_16x16x32_bf16(kf[rb][0], qf[cb][0], acc, 0, 0, 0);
      acc = __builtin_amdgcn_mfma_f32_16x16x32_bf16(kf[rb][1], qf[cb][1], acc, 0, 0, 0);
      st[rb][cb] = acc;
    }

  // ======== V^T fragments from LDS (scatter complete; own wave) ===========
  bf16x8 vfr[4][2];
#pragma unroll
  for (int db = 0; db < 4; ++db)
#pragma unroll
    for (int jb = 0; jb < 2; ++jb)
      vfr[db][jb] =
          *(const bf16x8*)(vt_raw + swzV(db * 16 + m, jb * 32 + g * 8));

  // ======== gating, row-sum, normalizer; write C (bf16) ===================
  float ea_j[4][4];
#pragma unroll
  for (int rb = 0; rb < 4; ++rb) {
    const float4 ea4 = *(const float4*)&ea_sh[rb * 16 + g * 4];
    ea_j[rb][0] = ea4.x; ea_j[rb][1] = ea4.y;
    ea_j[rb][2] = ea4.z; ea_j[rb][3] = ea4.w;
  }

  float invr[4];
#pragma unroll
  for (int cb = 0; cb < 4; ++cb) {
    const int i = cb * 16 + m;
    const float ebv = eb_sh[i];
    float rs = 0.f;
    const int rbfill = cb | 1;  // zero-fill the jb ranges mm2 will read
#pragma unroll
    for (int rb = 0; rb < 4; ++rb) {
      if (rb > rbfill) continue;
      unsigned long long wp = 0ull;
      if (rb <= cb) {
#pragma unroll
        for (int e = 0; e < 4; ++e) {
          const int j = rb * 16 + g * 4 + e;
          const float val = (j <= i) ? st[rb][cb][e] * ea_j[rb][e] * ebv : 0.f;
          rs += val;
          wp |= (unsigned long long)bfbits(val) << (16 * e);
        }
      }
      *(unsigned long long*)(cs_raw + swzC(i, rb * 16 + g * 4)) = wp;
    }
    rs += __shfl_xor(rs, 16, 64);
    rs += __shfl_xor(rs, 32, 64);
    const float n = fmaxf(fabsf(rs), em_sh[i]);
    invr[cb] = 1.f / (n + 1e-6f);
  }

  // ======== mm2 (per-ib): H^T = V^T * C^T, scale + store ===================
#pragma unroll
  for (int ib = 0; ib < 4; ++ib) {
    const int i = ib * 16 + m;
    const bf16x8 c0 = *(const bf16x8*)(cs_raw + swzC(i, g * 8));
    f32x4 acc[4];
#pragma unroll
    for (int db = 0; db < 4; ++db) {
      f32x4 z = {0.f, 0.f, 0.f, 0.f};
      acc[db] = __builtin_amdgcn_mfma_f32_16x16x32_bf16(vfr[db][0], c0, z, 0, 0, 0);
    }
    if (ib >= 2) {
      const bf16x8 c1 = *(const bf16x8*)(cs_raw + swzC(i, 32 + g * 8));
#pragma unroll
      for (int db = 0; db < 4; ++db)
        acc[db] = __builtin_amdgcn_mfma_f32_16x16x32_bf16(vfr[db][1], c1, acc[db], 0, 0, 0);
    }
    const float iv = invr[ib];
    float* op = out + cbase + i * 64 + g * 4;
#pragma unroll
    for (int db = 0; db < 4; ++db) {
      const f32x4 hv = acc[db];
      *(float4*)(op + db * 16) =
          make_float4(hv[0] * iv, hv[1] * iv, hv[2] * iv, hv[3] * iv);
    }
  }
}

}  // namespace

extern "C" void kernel_launch(void* const* d_in, const int* in_sizes, int n_in,
                              void* d_out, int out_size, void* d_ws,
                              size_t ws_size, hipStream_t stream) {
  const float* q = (const float*)d_in[0];
  const float* k = (const float*)d_in[1];
  const float* v = (const float*)d_in[2];
  const float* ig = (const float*)d_in[3];
  const float* fg = (const float*)d_in[4];
  float* out = (float*)d_out;

  const int total = in_sizes[0];         // B*NH*S*DH
  const int nchunks = total / (L * DH);  // 2048
  mlstm_mfma<<<dim3(nchunks), dim3(64), 0, stream>>>(q, k, v, ig, fg, out);
}